// Round 1
// baseline (860.686 us; speedup 1.0000x reference)
//
#include <hip/hip_runtime.h>

// Sudoku GNN: 5x GCNConv (shared graph) + 2-layer MLP head.
// Strategy: build CSR once per launch (int atomics only), pull-based
// aggregation (no float atomics), aggregate on the narrow side of each layer.

#define NN    165888            // total nodes = 2048*81
#define NBAT  2048
#define EPER  1620
#define NEDGE (NBAT * EPER)     // 3,317,760
#define ETOT  (NEDGE + NN)      // 3,483,648 (with self loops)

// ---------------- preprocessing ----------------

__global__ __launch_bounds__(256) void k_hist(const int* __restrict__ ei,
                                              int* __restrict__ deg) {
  int e = blockIdx.x * 256 + threadIdx.x;
  if (e >= EPER) return;
  int b = blockIdx.y;
  int dst = ei[b * (2 * EPER) + EPER + e];
  atomicAdd(&deg[dst], 1);
}

// Per node: claim a contiguous CSR segment (order-free via global counter),
// write dinv and the self-loop entry, leave cursor for edge scatter.
__global__ __launch_bounds__(256) void k_alloc(const int* __restrict__ deg,
                                               int* __restrict__ counter,
                                               int* __restrict__ row_start,
                                               int* __restrict__ row_end,
                                               int* __restrict__ cursor,
                                               float* __restrict__ dinv,
                                               int2* __restrict__ cw) {
  int i = blockIdx.x * 256 + threadIdx.x;
  if (i >= NN) return;
  int d = deg[i] + 1;                    // + self loop
  int rs = atomicAdd(counter, d);
  row_start[i] = rs;
  row_end[i]   = rs + d;
  float di = rsqrtf((float)d);
  dinv[i] = di;
  cw[rs] = make_int2(i, __float_as_int(di * di));   // self loop, w = dinv^2
  cursor[i] = rs + 1;
}

__global__ __launch_bounds__(256) void k_scatter(const int* __restrict__ ei,
                                                 const float* __restrict__ dinv,
                                                 int* __restrict__ cursor,
                                                 int2* __restrict__ cw) {
  int e = blockIdx.x * 256 + threadIdx.x;
  if (e >= EPER) return;
  int b = blockIdx.y;
  int s = ei[b * (2 * EPER) + e];
  int d = ei[b * (2 * EPER) + EPER + e];
  float wv = dinv[s] * dinv[d];
  int p = atomicAdd(&cursor[d], 1);
  cw[p] = make_int2(s, __float_as_int(wv));
}

// ---------------- small row-parallel GEMM ----------------

template <int CI, int CO, bool ADDB, bool RELU>
__global__ __launch_bounds__(256) void k_gemm(const float* __restrict__ in,
                                              const float* __restrict__ W,
                                              const float* __restrict__ bias,
                                              float* __restrict__ out) {
  __shared__ float sW[CI * CO];
  __shared__ float sB[CO];
  int t = threadIdx.x;
  for (int k = t; k < CI * CO; k += 256) sW[k] = W[k];
  if (ADDB) { if (t < CO) sB[t] = bias[t]; }
  __syncthreads();
  int i = blockIdx.x * 256 + t;
  if (i >= NN) return;
  float r[CI];
#pragma unroll
  for (int k = 0; k < CI; ++k) r[k] = in[(size_t)i * CI + k];
  float acc[CO];
#pragma unroll
  for (int j = 0; j < CO; ++j) acc[j] = ADDB ? sB[j] : 0.0f;
#pragma unroll
  for (int k = 0; k < CI; ++k) {
    float rv = r[k];
#pragma unroll
    for (int j = 0; j < CO; ++j) acc[j] = fmaf(rv, sW[k * CO + j], acc[j]);
  }
#pragma unroll
  for (int j = 0; j < CO; ++j) {
    float v = acc[j];
    if (RELU) v = fmaxf(v, 0.0f);
    out[(size_t)i * CO + j] = v;
  }
}

// ---------------- pull-based aggregation ----------------
// C/4 lanes cooperate per node (float4 each); CSR reads broadcast within
// the lane-group; gathers of one node's row are contiguous 64/128B.

template <int C, bool BIASRELU>
__global__ __launch_bounds__(256) void k_agg(const float* __restrict__ h,
                                             const int* __restrict__ row_start,
                                             const int* __restrict__ row_end,
                                             const int2* __restrict__ cw,
                                             const float* __restrict__ bias,
                                             float* __restrict__ out) {
  constexpr int LG  = C / 4;       // lanes per node
  constexpr int NPB = 256 / LG;    // nodes per block
  int t  = threadIdx.x;
  int q  = t & (LG - 1);
  int nl = t / LG;
  int i  = blockIdx.x * NPB + nl;
  int rs = row_start[i];
  int re = row_end[i];
  float4 acc = make_float4(0.f, 0.f, 0.f, 0.f);
  const float* hq = h + (size_t)q * 4;
  int p = rs;
  for (; p + 2 <= re; p += 2) {           // unroll x2 for two in-flight gathers
    int2 e0 = cw[p];
    int2 e1 = cw[p + 1];
    float w0 = __int_as_float(e0.y);
    float w1 = __int_as_float(e1.y);
    float4 v0 = *(const float4*)(hq + (size_t)e0.x * C);
    float4 v1 = *(const float4*)(hq + (size_t)e1.x * C);
    acc.x = fmaf(w0, v0.x, acc.x); acc.y = fmaf(w0, v0.y, acc.y);
    acc.z = fmaf(w0, v0.z, acc.z); acc.w = fmaf(w0, v0.w, acc.w);
    acc.x = fmaf(w1, v1.x, acc.x); acc.y = fmaf(w1, v1.y, acc.y);
    acc.z = fmaf(w1, v1.z, acc.z); acc.w = fmaf(w1, v1.w, acc.w);
  }
  if (p < re) {
    int2 e0 = cw[p];
    float w0 = __int_as_float(e0.y);
    float4 v0 = *(const float4*)(hq + (size_t)e0.x * C);
    acc.x = fmaf(w0, v0.x, acc.x); acc.y = fmaf(w0, v0.y, acc.y);
    acc.z = fmaf(w0, v0.z, acc.z); acc.w = fmaf(w0, v0.w, acc.w);
  }
  if (BIASRELU) {
    float4 bb = *(const float4*)(bias + q * 4);
    acc.x = fmaxf(acc.x + bb.x, 0.f);
    acc.y = fmaxf(acc.y + bb.y, 0.f);
    acc.z = fmaxf(acc.z + bb.z, 0.f);
    acc.w = fmaxf(acc.w + bb.w, 0.f);
  }
  *(float4*)(out + (size_t)i * C + q * 4) = acc;
}

// ---------------- fused head MLP: relu(h@fW1+fb1)@fW2+fb2 ----------------

__global__ __launch_bounds__(256) void k_mlp(const float* __restrict__ h,
                                             const float* __restrict__ fW1,
                                             const float* __restrict__ fb1,
                                             const float* __restrict__ fW2,
                                             const float* __restrict__ fb2,
                                             float* __restrict__ out) {
  __shared__ float sW1[256], sW2[144], sB1[16], sB2[9];
  int t = threadIdx.x;
  sW1[t] = fW1[t];
  if (t < 144) sW2[t] = fW2[t];
  if (t < 16)  sB1[t] = fb1[t];
  if (t < 9)   sB2[t] = fb2[t];
  __syncthreads();
  int i = blockIdx.x * 256 + t;
  if (i >= NN) return;
  float r[16];
#pragma unroll
  for (int k = 0; k < 16; ++k) r[k] = h[(size_t)i * 16 + k];
  float z[16];
#pragma unroll
  for (int j = 0; j < 16; ++j) z[j] = sB1[j];
#pragma unroll
  for (int k = 0; k < 16; ++k) {
    float rv = r[k];
#pragma unroll
    for (int j = 0; j < 16; ++j) z[j] = fmaf(rv, sW1[k * 16 + j], z[j]);
  }
#pragma unroll
  for (int j = 0; j < 16; ++j) z[j] = fmaxf(z[j], 0.f);
  float o[9];
#pragma unroll
  for (int j = 0; j < 9; ++j) o[j] = sB2[j];
#pragma unroll
  for (int k = 0; k < 16; ++k) {
    float zv = z[k];
#pragma unroll
    for (int j = 0; j < 9; ++j) o[j] = fmaf(zv, sW2[k * 9 + j], o[j]);
  }
#pragma unroll
  for (int j = 0; j < 9; ++j) out[(size_t)i * 9 + j] = o[j];
}

// ---------------- launch ----------------

extern "C" void kernel_launch(void* const* d_in, const int* in_sizes, int n_in,
                              void* d_out, int out_size, void* d_ws, size_t ws_size,
                              hipStream_t stream) {
  const float* x   = (const float*)d_in[0];
  const int*   ei  = (const int*)d_in[1];
  const float* W1  = (const float*)d_in[2];
  const float* b1  = (const float*)d_in[3];
  const float* W2  = (const float*)d_in[4];
  const float* b2  = (const float*)d_in[5];
  const float* W3  = (const float*)d_in[6];
  const float* b3  = (const float*)d_in[7];
  const float* W4  = (const float*)d_in[8];
  const float* b4  = (const float*)d_in[9];
  const float* W5  = (const float*)d_in[10];
  const float* b5  = (const float*)d_in[11];
  const float* fW1 = (const float*)d_in[12];
  const float* fb1 = (const float*)d_in[13];
  const float* fW2 = (const float*)d_in[14];
  const float* fb2 = (const float*)d_in[15];
  float* out = (float*)d_out;

  char* ws = (char*)d_ws;
  size_t off = 0;
  auto alloc = [&](size_t bytes) -> char* {
    char* p = ws + off;
    off += (bytes + 255) & ~(size_t)255;
    return p;
  };
  int*   deg     = (int*)  alloc((size_t)NN * 4);
  int*   counter = (int*)  alloc(256);             // adjacent to deg for one memset
  int*   rs_     = (int*)  alloc((size_t)NN * 4);
  int*   re_     = (int*)  alloc((size_t)NN * 4);
  int*   cur     = (int*)  alloc((size_t)NN * 4);
  float* dinv    = (float*)alloc((size_t)NN * 4);
  int2*  cw      = (int2*) alloc((size_t)ETOT * 8);
  float* P16a    = (float*)alloc((size_t)NN * 16 * 4);
  float* P16b    = (float*)alloc((size_t)NN * 16 * 4);
  float* P32a    = (float*)alloc((size_t)NN * 32 * 4);
  float* P32b    = (float*)alloc((size_t)NN * 32 * 4);
  float* P64     = (float*)alloc((size_t)NN * 64 * 4);
  // total ~137.4 MB of ws

  hipMemsetAsync(deg, 0, (size_t)NN * 4 + 256, stream);  // deg + counter

  dim3 gE((EPER + 255) / 256, NBAT);
  k_hist<<<gE, 256, 0, stream>>>(ei, deg);
  k_alloc<<<(NN + 255) / 256, 256, 0, stream>>>(deg, counter, rs_, re_, cur, dinv, cw);
  k_scatter<<<gE, 256, 0, stream>>>(ei, dinv, cur, cw);

  const int gN = (NN + 255) / 256;  // 648
  // L1: t1 = x@W1 ; h1 = relu(Agg(t1)+b1)
  k_gemm<10, 16, false, false><<<gN, 256, 0, stream>>>(x, W1, nullptr, P16a);
  k_agg<16, true ><<<NN / 64, 256, 0, stream>>>(P16a, rs_, re_, cw, b1, P16b);
  // L2: a2 = Agg(h1) ; h2 = relu(a2@W2+b2)
  k_agg<16, false><<<NN / 64, 256, 0, stream>>>(P16b, rs_, re_, cw, nullptr, P16a);
  k_gemm<16, 32, true, true ><<<gN, 256, 0, stream>>>(P16a, W2, b2, P32a);
  // L3: a3 = Agg(h2) ; h3 = relu(a3@W3+b3)
  k_agg<32, false><<<NN / 32, 256, 0, stream>>>(P32a, rs_, re_, cw, nullptr, P32b);
  k_gemm<32, 64, true, true ><<<gN, 256, 0, stream>>>(P32b, W3, b3, P64);
  // L4: t4 = h3@W4 ; h4 = relu(Agg(t4)+b4)
  k_gemm<64, 32, false, false><<<gN, 256, 0, stream>>>(P64, W4, nullptr, P32a);
  k_agg<32, true ><<<NN / 32, 256, 0, stream>>>(P32a, rs_, re_, cw, b4, P32b);
  // L5: t5 = h4@W5 ; h5 = relu(Agg(t5)+b5)
  k_gemm<32, 16, false, false><<<gN, 256, 0, stream>>>(P32b, W5, nullptr, P16a);
  k_agg<16, true ><<<NN / 64, 256, 0, stream>>>(P16a, rs_, re_, cw, b5, P16b);
  // Head MLP
  k_mlp<<<gN, 256, 0, stream>>>(P16b, fW1, fb1, fW2, fb2, out);
}

// Round 2
// 711.657 us; speedup vs baseline: 1.2094x; 1.2094x over previous
//
#include <hip/hip_runtime.h>

// Sudoku GNN: 5x GCNConv (shared graph) + 2-layer MLP head.
// CSR built once per launch. Weight-free CSR: norm_ij = dinv_i*dinv_j factors,
// so producers pre-scale rows by dinv and aggs post-scale by dinv -> CSR is
// src-only (4B/edge), scatter needs no dinv loads and no atomics.

#define NN    165888            // total nodes = 2048*81
#define NBAT  2048
#define EPER  1620
#define NEDGE (NBAT * EPER)     // 3,317,760
#define ETOT  (NEDGE + NN)      // 3,483,648 (with self loops)

// ---------------- preprocessing ----------------

// rank[f] = arrival order among edges with same dst; also builds deg histogram.
__global__ __launch_bounds__(256) void k_rank(const int* __restrict__ ei,
                                              int* __restrict__ deg,
                                              int* __restrict__ rank) {
  int e = blockIdx.x * 256 + threadIdx.x;
  if (e >= EPER) return;
  int b = blockIdx.y;
  int dst = ei[b * (2 * EPER) + EPER + e];
  rank[b * EPER + e] = atomicAdd(&deg[dst], 1);
}

// Per node: claim contiguous CSR segment, write dinv and self-loop entry.
__global__ __launch_bounds__(256) void k_alloc(const int* __restrict__ deg,
                                               int* __restrict__ counter,
                                               int* __restrict__ row_start,
                                               int* __restrict__ row_end,
                                               float* __restrict__ dinv,
                                               int* __restrict__ csr) {
  int i = blockIdx.x * 256 + threadIdx.x;
  if (i >= NN) return;
  int d = deg[i] + 1;                    // + self loop
  int rs = atomicAdd(counter, d);
  row_start[i] = rs;
  row_end[i]   = rs + d;
  dinv[i] = rsqrtf((float)d);
  csr[rs] = i;                           // self loop
}

__global__ __launch_bounds__(256) void k_scatter(const int* __restrict__ ei,
                                                 const int* __restrict__ rank,
                                                 const int* __restrict__ row_start,
                                                 int* __restrict__ csr) {
  int e = blockIdx.x * 256 + threadIdx.x;
  if (e >= EPER) return;
  int b = blockIdx.y;
  int s = ei[b * (2 * EPER) + e];
  int d = ei[b * (2 * EPER) + EPER + e];
  int r = rank[b * EPER + e];
  csr[row_start[d] + 1 + r] = s;         // no atomic, 1 random load + 1 random store
}

// ---------------- small row-parallel GEMM ----------------

template <int CI, int CO, bool ADDB, bool RELU, bool SCALE>
__global__ __launch_bounds__(256) void k_gemm(const float* __restrict__ in,
                                              const float* __restrict__ W,
                                              const float* __restrict__ bias,
                                              const float* __restrict__ dinv,
                                              float* __restrict__ out) {
  __shared__ float sW[CI * CO];
  __shared__ float sB[CO];
  int t = threadIdx.x;
  for (int k = t; k < CI * CO; k += 256) sW[k] = W[k];
  if (ADDB) { if (t < CO) sB[t] = bias[t]; }
  __syncthreads();
  int i = blockIdx.x * 256 + t;
  if (i >= NN) return;
  float r[CI];
#pragma unroll
  for (int k = 0; k < CI; ++k) r[k] = in[(size_t)i * CI + k];
  float acc[CO];
#pragma unroll
  for (int j = 0; j < CO; ++j) acc[j] = ADDB ? sB[j] : 0.0f;
#pragma unroll
  for (int k = 0; k < CI; ++k) {
    float rv = r[k];
#pragma unroll
    for (int j = 0; j < CO; ++j) acc[j] = fmaf(rv, sW[k * CO + j], acc[j]);
  }
  float sc = SCALE ? dinv[i] : 1.0f;
#pragma unroll
  for (int j = 0; j < CO; ++j) {
    float v = acc[j];
    if (RELU) v = fmaxf(v, 0.0f);
    if (SCALE) v *= sc;
    out[(size_t)i * CO + j] = v;
  }
}

// Fused: h3 = relu(a3@W3+b3);  g4 = dinv ⊙ (h3@W4)   (32 -> 64 -> 32)
__global__ __launch_bounds__(256) void k_gemm34(const float* __restrict__ in,
                                                const float* __restrict__ W3,
                                                const float* __restrict__ b3,
                                                const float* __restrict__ W4,
                                                const float* __restrict__ dinv,
                                                float* __restrict__ out) {
  __shared__ float sW3[32 * 64];
  __shared__ float sW4[64 * 32];
  __shared__ float sB3[64];
  int t = threadIdx.x;
  for (int k = t; k < 2048; k += 256) { sW3[k] = W3[k]; sW4[k] = W4[k]; }
  if (t < 64) sB3[t] = b3[t];
  __syncthreads();
  int i = blockIdx.x * 256 + t;
  if (i >= NN) return;
  float r[32];
#pragma unroll
  for (int k = 0; k < 32; ++k) r[k] = in[(size_t)i * 32 + k];
  float h[64];
#pragma unroll
  for (int j = 0; j < 64; ++j) h[j] = sB3[j];
#pragma unroll
  for (int k = 0; k < 32; ++k) {
    float rv = r[k];
#pragma unroll
    for (int j = 0; j < 64; ++j) h[j] = fmaf(rv, sW3[k * 64 + j], h[j]);
  }
#pragma unroll
  for (int j = 0; j < 64; ++j) h[j] = fmaxf(h[j], 0.0f);
  float acc[32];
#pragma unroll
  for (int j = 0; j < 32; ++j) acc[j] = 0.0f;
#pragma unroll
  for (int k = 0; k < 64; ++k) {
    float hv = h[k];
#pragma unroll
    for (int j = 0; j < 32; ++j) acc[j] = fmaf(hv, sW4[k * 32 + j], acc[j]);
  }
  float sc = dinv[i];
#pragma unroll
  for (int j = 0; j < 32; ++j) out[(size_t)i * 32 + j] = acc[j] * sc;
}

// ---------------- pull-based aggregation (weight-free) ----------------
// LG = C/4 lanes per node, float4 each. CSR loads are group-cooperative
// (coalesced) and distributed via shuffles; 8 gathers kept in flight.

template <int C, bool BIASRELU, bool OUTSCALE>
__global__ __launch_bounds__(256) void k_agg(const float* __restrict__ g,
                                             const int* __restrict__ row_start,
                                             const int* __restrict__ row_end,
                                             const int* __restrict__ csr,
                                             const float* __restrict__ dinv,
                                             const float* __restrict__ bias,
                                             float* __restrict__ out) {
  constexpr int LG  = C / 4;       // lanes per node
  constexpr int NPB = 256 / LG;    // nodes per block
  constexpr int EPI = 8;           // edges in flight per iteration
  int t  = threadIdx.x;
  int q  = t & (LG - 1);
  int i  = blockIdx.x * NPB + t / LG;
  int gl = (t & 63) & ~(LG - 1);   // group base lane within wave
  int rs = row_start[i];
  int re = row_end[i];
  float4 acc = make_float4(0.f, 0.f, 0.f, 0.f);
  const float* gq = g + (size_t)q * 4;
  for (int p = rs; p < re; p += EPI) {
    int myv[EPI / LG];
#pragma unroll
    for (int u = 0; u < EPI / LG; ++u) {
      int idx = p + u * LG + q;
      myv[u] = csr[idx < re ? idx : re - 1];
    }
#pragma unroll
    for (int j = 0; j < EPI; ++j) {
      if (p + j >= re) break;                      // uniform within lane-group
      int s = __shfl(myv[j / LG], gl + (j & (LG - 1)));
      float4 v = *(const float4*)(gq + (size_t)s * C);
      acc.x += v.x; acc.y += v.y; acc.z += v.z; acc.w += v.w;
    }
  }
  float di = dinv[i];
  acc.x *= di; acc.y *= di; acc.z *= di; acc.w *= di;
  if (BIASRELU) {
    float4 bb = *(const float4*)(bias + q * 4);
    acc.x = fmaxf(acc.x + bb.x, 0.f);
    acc.y = fmaxf(acc.y + bb.y, 0.f);
    acc.z = fmaxf(acc.z + bb.z, 0.f);
    acc.w = fmaxf(acc.w + bb.w, 0.f);
  }
  if (OUTSCALE) { acc.x *= di; acc.y *= di; acc.z *= di; acc.w *= di; }
  *(float4*)(out + (size_t)i * C + q * 4) = acc;
}

// ---------------- fused head MLP: relu(h@fW1+fb1)@fW2+fb2 ----------------

__global__ __launch_bounds__(256) void k_mlp(const float* __restrict__ h,
                                             const float* __restrict__ fW1,
                                             const float* __restrict__ fb1,
                                             const float* __restrict__ fW2,
                                             const float* __restrict__ fb2,
                                             float* __restrict__ out) {
  __shared__ float sW1[256], sW2[144], sB1[16], sB2[9];
  int t = threadIdx.x;
  sW1[t] = fW1[t];
  if (t < 144) sW2[t] = fW2[t];
  if (t < 16)  sB1[t] = fb1[t];
  if (t < 9)   sB2[t] = fb2[t];
  __syncthreads();
  int i = blockIdx.x * 256 + t;
  if (i >= NN) return;
  float r[16];
#pragma unroll
  for (int k = 0; k < 16; ++k) r[k] = h[(size_t)i * 16 + k];
  float z[16];
#pragma unroll
  for (int j = 0; j < 16; ++j) z[j] = sB1[j];
#pragma unroll
  for (int k = 0; k < 16; ++k) {
    float rv = r[k];
#pragma unroll
    for (int j = 0; j < 16; ++j) z[j] = fmaf(rv, sW1[k * 16 + j], z[j]);
  }
#pragma unroll
  for (int j = 0; j < 16; ++j) z[j] = fmaxf(z[j], 0.f);
  float o[9];
#pragma unroll
  for (int j = 0; j < 9; ++j) o[j] = sB2[j];
#pragma unroll
  for (int k = 0; k < 16; ++k) {
    float zv = z[k];
#pragma unroll
    for (int j = 0; j < 9; ++j) o[j] = fmaf(zv, sW2[k * 9 + j], o[j]);
  }
#pragma unroll
  for (int j = 0; j < 9; ++j) out[(size_t)i * 9 + j] = o[j];
}

// ---------------- launch ----------------

extern "C" void kernel_launch(void* const* d_in, const int* in_sizes, int n_in,
                              void* d_out, int out_size, void* d_ws, size_t ws_size,
                              hipStream_t stream) {
  const float* x   = (const float*)d_in[0];
  const int*   ei  = (const int*)d_in[1];
  const float* W1  = (const float*)d_in[2];
  const float* b1  = (const float*)d_in[3];
  const float* W2  = (const float*)d_in[4];
  const float* b2  = (const float*)d_in[5];
  const float* W3  = (const float*)d_in[6];
  const float* b3  = (const float*)d_in[7];
  const float* W4  = (const float*)d_in[8];
  const float* b4  = (const float*)d_in[9];
  const float* W5  = (const float*)d_in[10];
  const float* b5  = (const float*)d_in[11];
  const float* fW1 = (const float*)d_in[12];
  const float* fb1 = (const float*)d_in[13];
  const float* fW2 = (const float*)d_in[14];
  const float* fb2 = (const float*)d_in[15];
  float* out = (float*)d_out;

  char* ws = (char*)d_ws;
  size_t off = 0;
  auto alloc = [&](size_t bytes) -> char* {
    char* p = ws + off;
    off += (bytes + 255) & ~(size_t)255;
    return p;
  };
  int*   deg     = (int*)  alloc((size_t)NN * 4);
  int*   counter = (int*)  alloc(256);             // adjacent to deg: one memset
  int*   rank    = (int*)  alloc((size_t)NEDGE * 4);
  int*   rs_     = (int*)  alloc((size_t)NN * 4);
  int*   re_     = (int*)  alloc((size_t)NN * 4);
  float* dinv    = (float*)alloc((size_t)NN * 4);
  int*   csr     = (int*)  alloc((size_t)ETOT * 4);
  float* P16a    = (float*)alloc((size_t)NN * 16 * 4);
  float* P16b    = (float*)alloc((size_t)NN * 16 * 4);
  float* P32a    = (float*)alloc((size_t)NN * 32 * 4);
  float* P32b    = (float*)alloc((size_t)NN * 32 * 4);
  // total ~94 MB of ws

  hipMemsetAsync(deg, 0, (size_t)NN * 4 + 256, stream);  // deg + counter

  dim3 gE((EPER + 255) / 256, NBAT);
  k_rank<<<gE, 256, 0, stream>>>(ei, deg, rank);
  k_alloc<<<(NN + 255) / 256, 256, 0, stream>>>(deg, counter, rs_, re_, dinv, csr);
  k_scatter<<<gE, 256, 0, stream>>>(ei, rank, rs_, csr);

  const int gN = (NN + 255) / 256;  // 648
  // L1: g0 = dinv⊙(x@W1); g1 = dinv⊙relu(dinv*Σg0 + b1)
  k_gemm<10, 16, false, false, true><<<gN, 256, 0, stream>>>(x, W1, nullptr, dinv, P16a);
  k_agg<16, true, true ><<<NN / 64, 256, 0, stream>>>(P16a, rs_, re_, csr, dinv, b1, P16b);
  // L2: a2 = dinv*Σg1 ; g2 = dinv⊙relu(a2@W2+b2)
  k_agg<16, false, false><<<NN / 64, 256, 0, stream>>>(P16b, rs_, re_, csr, dinv, nullptr, P16a);
  k_gemm<16, 32, true, true, true><<<gN, 256, 0, stream>>>(P16a, W2, b2, dinv, P32a);
  // L3+L4 front: a3 = dinv*Σg2 ; h3 = relu(a3@W3+b3); g4 = dinv⊙(h3@W4)
  k_agg<32, false, false><<<NN / 32, 256, 0, stream>>>(P32a, rs_, re_, csr, dinv, nullptr, P32b);
  k_gemm34<<<gN, 256, 0, stream>>>(P32b, W3, b3, W4, dinv, P32a);
  // L4 agg: h4 = relu(dinv*Σg4 + b4)
  k_agg<32, true, false><<<NN / 32, 256, 0, stream>>>(P32a, rs_, re_, csr, dinv, b4, P32b);
  // L5: g5 = dinv⊙(h4@W5); h5 = relu(dinv*Σg5 + b5)
  k_gemm<32, 16, false, false, true><<<gN, 256, 0, stream>>>(P32b, W5, nullptr, dinv, P16a);
  k_agg<16, true, false><<<NN / 64, 256, 0, stream>>>(P16a, rs_, re_, csr, dinv, b5, P16b);
  // Head MLP
  k_mlp<<<gN, 256, 0, stream>>>(P16b, fW1, fb1, fW2, fb2, out);
}